// Round 16
// baseline (233.691 us; speedup 1.0000x reference)
//
#include <hip/hip_runtime.h>
#include <cstdio>

// ---------------------------------------------------------------------------
// PairAttnDecoderRNN forward, MI355X/gfx950.  Round 16 = Round 15 (220.6us) +
// gemm24p: full-K + 3-deep counted-vmcnt pipeline:
//  - 3 LDS buffer-pairs (48KB, 3 blk/CU) -> each load gets TWO compute phases
//    in flight (vmcnt(8) steady state); grid 640 = one dispatch round exactly.
//  - full-K kills split-K2's 21MB partial write + 21MB scores re-read (~6us);
//    scores kernels revert to the round-11-proven single-key versions.
//  - XCD remap kept: xcd owns one GEMM half and 10 contiguous A-panels.
//  11 launches.
// ---------------------------------------------------------------------------

using f32x4   = __attribute__((ext_vector_type(4))) float;
using bf16x8  = __attribute__((ext_vector_type(8))) short;
using ushort8 = __attribute__((ext_vector_type(8))) unsigned short;

__device__ __forceinline__ unsigned short f2bf(float x) {
    unsigned u = __builtin_bit_cast(unsigned, x);
    u += 0x7fffu + ((u >> 16) & 1u);          // RNE
    return (unsigned short)(u >> 16);
}
__device__ __forceinline__ float bf2f(unsigned short u) {
    return __builtin_bit_cast(float, ((unsigned)u) << 16);
}

// async global->LDS, 16B per lane. LDS dest = wave-uniform base + lane*16.
__device__ __forceinline__ void gload16(const void* g, void* l) {
    auto gp = (const __attribute__((address_space(1))) void*)g;
    auto lp = (__attribute__((address_space(3))) void*)l;
    __builtin_amdgcn_global_load_lds(gp, lp, 16, 0, 0);
}

// ---------------- (R,C) fp32 -> (C,R) bf16 transpose body, 128r x 32c tile --
__device__ __forceinline__ void transpose_body(
    const float* __restrict__ in, unsigned short* __restrict__ out,
    int R, int C, int r0, int c0)
{
    __shared__ float t[32][129];
    const int tid = threadIdx.x;
    const int lr = tid >> 3;              // 0..31
    const int cc = (tid & 7) * 4;         // col chunk
    #pragma unroll
    for (int i = 0; i < 4; ++i) {
        int r = lr + 32 * i;
        float4 v = *(const float4*)(in + (size_t)(r0 + r) * C + c0 + cc);
        t[cc + 0][r] = v.x; t[cc + 1][r] = v.y;
        t[cc + 2][r] = v.z; t[cc + 3][r] = v.w;
    }
    __syncthreads();
    const int rc = (tid & 15) * 8;        // r chunk (8 outputs = 16B store)
    #pragma unroll
    for (int p = 0; p < 2; ++p) {
        int c = (tid >> 4) + 16 * p;
        const float* src = &t[c][rc];
        ushort8 o;
        #pragma unroll
        for (int j = 0; j < 8; ++j) o[j] = f2bf(src[j]);
        *(ushort8*)(out + (size_t)(c0 + c) * R + r0 + rc) = o;
    }
}

// ---------------- prep1: all input converts + Wq/Wk transposes --------------
__global__ __launch_bounds__(256) void prep1_kernel(
    const float* __restrict__ hidden, const float* __restrict__ enc_out,
    const float* __restrict__ enc_emb,
    const float* __restrict__ Wq_i, const float* __restrict__ Wq_p,
    const float* __restrict__ Wk_i, const float* __restrict__ Wk_p,
    unsigned short* __restrict__ hb, unsigned short* __restrict__ encb,
    unsigned short* __restrict__ encembb,
    unsigned short* __restrict__ WqiT, unsigned short* __restrict__ WqpT,
    unsigned short* __restrict__ WkiT, unsigned short* __restrict__ WkpT)
{
    const int bid = blockIdx.x;
    if (bid < 20496) {
        int i = bid * 256 + threadIdx.x;   // total 5,246,976 quads
        const float* src; unsigned short* dst; int j;
        if (i < 65536)        { src = hidden;  dst = hb;      j = i; }
        else if (i < 2686976) { src = enc_out; dst = encb;    j = i - 65536; }
        else                  { src = enc_emb; dst = encembb; j = i - 2686976; }
        float4 v = ((const float4*)src)[j];
        ((ushort4*)dst)[j] = make_ushort4(f2bf(v.x), f2bf(v.y), f2bf(v.z), f2bf(v.w));
    } else if (bid < 21008) {
        int local = bid - 20496;           // 512: z(2) x by(8) x bx(32)
        int bz = local >> 8, rem = local & 255;
        transpose_body(bz ? Wq_p : Wq_i, bz ? WqpT : WqiT,
                       1024, 1024, (rem >> 5) * 128, (rem & 31) * 32);
    } else {
        int local = bid - 21008;           // 1024: z(2) x by(16) x bx(32)
        int bz = local >> 9, rem = local & 511;
        transpose_body(bz ? Wk_p : Wk_i, bz ? WkpT : WkiT,
                       2048, 1024, (rem >> 5) * 128, (rem & 31) * 32);
    }
}

// ---------------- bf16 MFMA GEMM core: C(M,N) = A(M,K) * Bt(N,K)^T ----------
// 128x128 tile, BK=64, 4 waves 2x2, 16x16x32 MFMA, global_load_lds width=16.
// SINGLE-buffered 32KB LDS (m97 structure): {stage; bar; compute; bar}.
template<int OUTBF, bool HAS_BIAS>
__device__ __forceinline__ void gemm_core(
    const unsigned short* __restrict__ A, const unsigned short* __restrict__ Bt,
    const float* __restrict__ bias, void* __restrict__ Cout, int Ncols,
    int sA, int sB, int kLen, int m0, int n0,
    unsigned short* lA, unsigned short* lB)
{
    const int tid = threadIdx.x;
    const int lane = tid & 63, wave = tid >> 6;
    const int wr = wave >> 1, wc = wave & 1;
    const int srow = tid >> 3, schunk = tid & 7;
    const int lm = lane & 15, lk = (lane >> 4) * 8;

    f32x4 acc[4][4];
    #pragma unroll
    for (int m = 0; m < 4; ++m)
        #pragma unroll
        for (int n = 0; n < 4; ++n) { f32x4 z = {0.f,0.f,0.f,0.f}; acc[m][n] = z; }

    const unsigned short* Ag = A  + (size_t)(m0 + srow) * sA + schunk * 8;
    const unsigned short* Bg = Bt + (size_t)(n0 + srow) * sB + schunk * 8;
    const int nt = kLen >> 6;

    char* lap = (char*)lA + tid * 16;
    char* lbp = (char*)lB + tid * 16;

    for (int t = 0; t < nt; ++t) {
        #pragma unroll
        for (int i = 0; i < 4; ++i) {
            gload16(Ag + (size_t)(32 * i) * sA + t * 64, lap + i * 4096);
            gload16(Bg + (size_t)(32 * i) * sB + t * 64, lbp + i * 4096);
        }
        __syncthreads();
        #pragma unroll
        for (int kk = 0; kk < 2; ++kk) {
            bf16x8 af[4], bv[4];
            #pragma unroll
            for (int m = 0; m < 4; ++m)
                af[m] = *(const bf16x8*)((const char*)lA +
                          (wr * 64 + m * 16 + lm) * 128 + (kk * 32 + lk) * 2);
            #pragma unroll
            for (int n = 0; n < 4; ++n)
                bv[n] = *(const bf16x8*)((const char*)lB +
                          (wc * 64 + n * 16 + lm) * 128 + (kk * 32 + lk) * 2);
            #pragma unroll
            for (int m = 0; m < 4; ++m)
                #pragma unroll
                for (int n = 0; n < 4; ++n)
                    acc[m][n] = __builtin_amdgcn_mfma_f32_16x16x32_bf16(
                        af[m], bv[n], acc[m][n], 0, 0, 0);
        }
        __syncthreads();
    }

    // epilogue: C/D layout col=lane&15, row=(lane>>4)*4+j  [m89/m91 verified]
    const int rbase = m0 + wr * 64 + (lane >> 4) * 4;
    const int cbase = n0 + wc * 64 + lm;
    #pragma unroll
    for (int m = 0; m < 4; ++m) {
        #pragma unroll
        for (int n = 0; n < 4; ++n) {
            int col = cbase + n * 16;
            float bvv = HAS_BIAS ? bias[col] : 0.0f;
            #pragma unroll
            for (int j = 0; j < 4; ++j) {
                int row = rbase + m * 16 + j;
                float v = acc[m][n][j] + bvv;
                if (OUTBF)
                    ((unsigned short*)Cout)[(size_t)row * Ncols + col] = f2bf(v);
                else
                    ((float*)Cout)[(size_t)row * Ncols + col] = v;
            }
        }
    }
}

#define GEMM_SHARED \
    __shared__ unsigned short lA[8192]; __shared__ unsigned short lB[8192];

// G1+G3 merged, split-K4: z = g*4+s; partials f32 -> P{g} + s*262144
__global__ __launch_bounds__(256) void gemm_dual_kernel(
    const unsigned short* A, const unsigned short* B0, const unsigned short* B1,
    float* P0, float* P1)
{
    GEMM_SHARED
    const int g = blockIdx.z >> 2, s = blockIdx.z & 3;
    const unsigned short* Bt = (g ? B1 : B0) + s * 256;
    float* C = (g ? P1 : P0) + (size_t)s * 262144;
    gemm_core<0,false>(A + s * 256, Bt, nullptr, C, 1024, 1024, 1024, 256,
                       blockIdx.y * 128, blockIdx.x * 128, lA, lB);
}

// ---------------- gemm24p3: G4'+G2 merged, FULL-K, 3-deep dbuf --------------
// COUNTED-VMCNT (T4, vmcnt(8): two tiles in flight) + XCD remap (T1).
// grid 640 = 8 XCD x 80; xcd>>2 selects GEMM, (xcd&3)*10 + r>>3 the A-panel.
// LDS 3 x (8KB A + 8KB B) = 48KB -> 3 blk/CU, 640 <= 768 one dispatch round.
__global__ __launch_bounds__(256) void gemm24p3_kernel(
    const unsigned short* encembb, const unsigned short* encb,
    const unsigned short* WkpT, const unsigned short* WkiT,
    unsigned short* kp_all, unsigned short* key)
{
    __shared__ unsigned short lA0[4096]; __shared__ unsigned short lA1[4096];
    __shared__ unsigned short lA2[4096];
    __shared__ unsigned short lB0[4096]; __shared__ unsigned short lB1[4096];
    __shared__ unsigned short lB2[4096];
    const int w   = (int)blockIdx.x;
    const int xcd = w & 7;
    const int r   = w >> 3;                   // 0..79
    const int g   = xcd >> 2;                 // 0..1
    const int by  = (xcd & 3) * 10 + (r >> 3);// 0..39
    const int bx  = r & 7;                    // 0..7
    const unsigned short* A  = g ? encb : encembb;
    const unsigned short* Bt = g ? WkiT : WkpT;
    unsigned short* Cb = g ? key : kp_all;
    const int m0 = by * 128, n0 = bx * 128;
    const int tid = threadIdx.x;
    const int lane = tid & 63, wave = tid >> 6;
    const int wr = wave >> 1, wc = wave & 1;
    const int lm = lane & 15;
    const int q  = lane >> 4;                 // k-chunk 0..3 (8 elems each)
    const int srow = tid >> 2;                // 0..63 (also +64 for 2nd gload)
    const int sc   = (tid & 3) ^ (srow & 3);  // pre-swizzled global chunk

    f32x4 acc[4][4];
    #pragma unroll
    for (int m = 0; m < 4; ++m)
        #pragma unroll
        for (int n = 0; n < 4; ++n) { f32x4 zz = {0.f,0.f,0.f,0.f}; acc[m][n] = zz; }

    const unsigned short* Ag = A  + (size_t)(m0 + srow) * 2048 + sc * 8;
    const unsigned short* Bg = Bt + (size_t)(n0 + srow) * 2048 + sc * 8;

    auto stage = [&](unsigned short* la_, unsigned short* lb_, int t) {
        char* pa = (char*)la_ + tid * 16;
        char* pb = (char*)lb_ + tid * 16;
        gload16(Ag + t * 32, pa);
        gload16(Ag + (size_t)64 * 2048 + t * 32, pa + 4096);
        gload16(Bg + t * 32, pb);
        gload16(Bg + (size_t)64 * 2048 + t * 32, pb + 4096);
    };
    auto compute = [&](const unsigned short* la_, const unsigned short* lb_) {
        bf16x8 af[4], bv[4];
        #pragma unroll
        for (int m = 0; m < 4; ++m) {
            int rr = wr * 64 + m * 16 + lm;
            af[m] = *(const bf16x8*)((const char*)la_ + rr * 64 + ((q ^ (rr & 3)) * 16));
        }
        #pragma unroll
        for (int n = 0; n < 4; ++n) {
            int rr = wc * 64 + n * 16 + lm;
            bv[n] = *(const bf16x8*)((const char*)lb_ + rr * 64 + ((q ^ (rr & 3)) * 16));
        }
        #pragma unroll
        for (int m = 0; m < 4; ++m)
            #pragma unroll
            for (int n = 0; n < 4; ++n)
                acc[m][n] = __builtin_amdgcn_mfma_f32_16x16x32_bf16(
                    af[m], bv[n], acc[m][n], 0, 0, 0);
    };
    #define BAR() __builtin_amdgcn_s_barrier(); __builtin_amdgcn_sched_barrier(0)
    #define WAIT8() asm volatile("s_waitcnt vmcnt(8)" ::: "memory")

    // prologue: tiles 0,1,2 in flight (12 loads); wait oldest 4 (tile 0).
    stage(lA0, lB0, 0);
    stage(lA1, lB1, 1);
    stage(lA2, lB2, 2);
    WAIT8();                                   // tile-0 loads done
    BAR();

    // main loop: computes tiles 0..59, stages 3..62 (kLen=2048 -> 64 tiles).
    for (int t = 0; t < 60; t += 3) {
        compute(lA0, lB0);                     // tile t
        BAR();                                 // WAR: all done reading b0
        stage(lA0, lB0, t + 3);                // outstanding: 12
        WAIT8();                               // tile t+1 done
        BAR();                                 // b1 ready block-wide

        compute(lA1, lB1);                     // tile t+1
        BAR();
        stage(lA1, lB1, t + 4);
        WAIT8();                               // tile t+2 done
        BAR();

        compute(lA2, lB2);                     // tile t+2
        BAR();
        stage(lA2, lB2, t + 5);
        WAIT8();                               // tile t+3 done
        BAR();
    }
    // tail: tiles 60..63 (61,62 in flight; 63 staged below)
    compute(lA0, lB0);                         // tile 60
    BAR();
    stage(lA0, lB0, 63);                       // outstanding: 12
    WAIT8();                                   // tile 61 done
    BAR();
    compute(lA1, lB1);                         // tile 61
    asm volatile("s_waitcnt vmcnt(4)" ::: "memory");   // tile 62 done
    BAR();
    compute(lA2, lB2);                         // tile 62
    asm volatile("s_waitcnt vmcnt(0)" ::: "memory");   // tile 63 done
    BAR();
    compute(lA0, lB0);                         // tile 63
    #undef BAR
    #undef WAIT8

    // epilogue: C/D layout col=lane&15, row=(lane>>4)*4+j
    const int rbase = m0 + wr * 64 + q * 4;
    const int cbase = n0 + wc * 64 + lm;
    #pragma unroll
    for (int m = 0; m < 4; ++m)
        #pragma unroll
        for (int n = 0; n < 4; ++n)
            #pragma unroll
            for (int j = 0; j < 4; ++j)
                Cb[(size_t)(rbase + m * 16 + j) * 1024 + cbase + n * 16] =
                    f2bf(acc[m][n][j]);
}

// ---------------- ingredient scores: q = sum of 4 pqQ slices, key full ------
__global__ __launch_bounds__(256) void attn_scores_q_kernel(
    const float* __restrict__ pqQ, const unsigned short* __restrict__ key,
    const float* __restrict__ wa, float* __restrict__ scores)
{
    const int bm = blockIdx.x;          // b*20 + m
    const int b  = bm / 20;
    const int tid = threadIdx.x;
    float4 qa = ((const float4*)(pqQ + (size_t)b * 1024))[tid];
    float4 qb = ((const float4*)(pqQ + 262144 + (size_t)b * 1024))[tid];
    float4 qc = ((const float4*)(pqQ + 524288 + (size_t)b * 1024))[tid];
    float4 qd = ((const float4*)(pqQ + 786432 + (size_t)b * 1024))[tid];
    float4 qv = make_float4(qa.x + qb.x + qc.x + qd.x, qa.y + qb.y + qc.y + qd.y,
                            qa.z + qb.z + qc.z + qd.z, qa.w + qb.w + qc.w + qd.w);
    ushort4 kv = ((const ushort4*)(key + (size_t)bm * 1024))[tid];
    float4 wv  = ((const float4*)wa)[tid];
    float p = tanhf(qv.x + bf2f(kv.x)) * wv.x + tanhf(qv.y + bf2f(kv.y)) * wv.y
            + tanhf(qv.z + bf2f(kv.z)) * wv.z + tanhf(qv.w + bf2f(kv.w)) * wv.w;
    #pragma unroll
    for (int off = 32; off > 0; off >>= 1) p += __shfl_down(p, off);
    __shared__ float sp[4];
    if ((tid & 63) == 0) sp[tid >> 6] = p;
    __syncthreads();
    if (tid == 0) scores[bm] = sp[0] + sp[1] + sp[2] + sp[3];
}

// argmax over ingredient scores (first-max tiebreak = jnp) -> ingredient id
__device__ __forceinline__ int argmax_ing(
    const float* __restrict__ sc_i, const int* __restrict__ input_tensor, int b)
{
    float best = sc_i[b * 20]; int bi = 0;
    #pragma unroll
    for (int m = 1; m < 20; ++m) {
        float v = sc_i[b * 20 + m];
        if (v > best) { best = v; bi = m; }
    }
    return input_tensor[b * 20 + bi];
}

// ---------------- pairing scores: q_p from 4 pqP slices; gather kp_all ------
__global__ __launch_bounds__(256) void attn_scores_gather_q_kernel(
    const float* __restrict__ pqP, const unsigned short* __restrict__ kp_all,
    const float* __restrict__ wa, const float* __restrict__ ba,
    const float* __restrict__ sc_i, const int* __restrict__ input_tensor,
    const int* __restrict__ pairing_ids, float* __restrict__ scores)
{
    const int bm = blockIdx.x;          // b*20 + k
    const int b  = bm / 20;
    const int kk = bm - b * 20;
    const int tid = threadIdx.x;
    const int ing = argmax_ing(sc_i, input_tensor, b);
    const int cid = pairing_ids[ing * 20 + kk];
    float4 qa = ((const float4*)(pqP + (size_t)b * 1024))[tid];
    float4 qb = ((const float4*)(pqP + 262144 + (size_t)b * 1024))[tid];
    float4 qc = ((const float4*)(pqP + 524288 + (size_t)b * 1024))[tid];
    float4 qd = ((const float4*)(pqP + 786432 + (size_t)b * 1024))[tid];
    float4 qv = make_float4(qa.x + qb.x + qc.x + qd.x, qa.y + qb.y + qc.y + qd.y,
                            qa.z + qb.z + qc.z + qd.z, qa.w + qb.w + qc.w + qd.w);
    ushort4 kv = ((const ushort4*)(kp_all + (size_t)cid * 1024))[tid];
    float4 wv  = ((const float4*)wa)[tid];
    float p = tanhf(qv.x + bf2f(kv.x)) * wv.x + tanhf(qv.y + bf2f(kv.y)) * wv.y
            + tanhf(qv.z + bf2f(kv.z)) * wv.z + tanhf(qv.w + bf2f(kv.w)) * wv.w;
    #pragma unroll
    for (int off = 32; off > 0; off >>= 1) p += __shfl_down(p, off);
    __shared__ float sp[4];
    if ((tid & 63) == 0) sp[tid >> 6] = p;
    __syncthreads();
    if (tid == 0) scores[bm] = sp[0] + sp[1] + sp[2] + sp[3] + ba[0];
}

// ---------------- out_pair assembly (softmax*s + enc_emb gather folded) -----
__global__ __launch_bounds__(256) void out_pair_kernel(
    const float* __restrict__ s_p, const float* __restrict__ enc_emb,
    const float* __restrict__ sc_i, const int* __restrict__ input_tensor,
    const int* __restrict__ pairing_ids,
    const float* __restrict__ emb_dec, const int* __restrict__ input_ids,
    unsigned short* __restrict__ out_pairb)
{
    const int b = blockIdx.x / 6, seg = blockIdx.x % 6;
    const int tid = threadIdx.x;
    const int d = seg * 512 + tid * 2;
    ushort2 o;
    if (seg < 2) {                       // emb part, d < 1024
        float2 v = *(const float2*)(emb_dec + (size_t)input_ids[b] * 1024 + d);
        o.x = f2bf(v.x); o.y = f2bf(v.y);
    } else {                             // attn_app part: gather enc_emb f32
        const int ing = argmax_ing(sc_i, input_tensor, b);
        __shared__ float s_raw[20];
        if (tid < 20) s_raw[tid] = s_p[b * 20 + tid];
        __syncthreads();
        float mx = -1e30f;
        #pragma unroll
        for (int m = 0; m < 20; ++m) mx = fmaxf(mx, s_raw[m]);
        float den = 0.f; float w[20];
        #pragma unroll
        for (int m = 0; m < 20; ++m) { w[m] = expf(s_raw[m] - mx); den += w[m]; }
        const float inv = 1.f / den;
        const int dd = d - 1024;
        float a0 = 0.f, a1 = 0.f;
        #pragma unroll
        for (int k = 0; k < 20; ++k) {
            const int cid = pairing_ids[ing * 20 + k];
            float2 v = *(const float2*)(enc_emb + (size_t)cid * 2048 + dd);
            float a = w[k] * inv * s_raw[k];           // softmax * raw score
            a0 += a * v.x; a1 += a * v.y;
        }
        o.x = f2bf(a0); o.y = f2bf(a1);
    }
    *(ushort2*)(out_pairb + (size_t)b * 3072 + d) = o;
}

// ---------------- G5 fused: x-partials = out_pair @ W_lin^T (W_lin f32) -----
// split-K16: z in [0,16), kLen 192 (3 tiles). Partials -> d_out scratch.
__global__ __launch_bounds__(256) void gemm5f_kernel(
    const unsigned short* __restrict__ A, const float* __restrict__ Wlin,
    float* __restrict__ P)
{
    __shared__ unsigned short lA[8192];
    __shared__ unsigned short lB[8192];
    const int tid = threadIdx.x;
    const int lane = tid & 63, wave = tid >> 6;
    const int wr = wave >> 1, wc = wave & 1;
    const int m0 = blockIdx.y * 128, n0 = blockIdx.x * 128;
    const int koff = blockIdx.z * 192;
    const int srow = tid >> 3, schunk = tid & 7;
    const int lm = lane & 15, lk = (lane >> 4) * 8;
    const int bcol = tid & 127, bkg = tid >> 7;    // B: col 0..127, k-half 0..1
    const int bsw  = (bcol & 7) << 4;

    f32x4 acc[4][4];
    #pragma unroll
    for (int m = 0; m < 4; ++m)
        #pragma unroll
        for (int n = 0; n < 4; ++n) { f32x4 z = {0.f,0.f,0.f,0.f}; acc[m][n] = z; }

    const unsigned short* Ag = A + (size_t)(m0 + srow) * 3072 + koff + schunk * 8;
    char* lap = (char*)lA + tid * 16;

    for (int t = 0; t < 3; ++t) {
        #pragma unroll
        for (int i = 0; i < 4; ++i)
            gload16(Ag + (size_t)(32 * i) * 3072 + t * 64, lap + i * 4096);
        #pragma unroll
        for (int hh = 0; hh < 2; ++hh) {
            const int kbase = koff + t * 64 + bkg * 32 + hh * 16;
            ushort8 o0, o1;
            #pragma unroll
            for (int j = 0; j < 8; ++j)
                o0[j] = f2bf(Wlin[(size_t)(kbase + j) * 2048 + n0 + bcol]);
            #pragma unroll
            for (int j = 0; j < 8; ++j)
                o1[j] = f2bf(Wlin[(size_t)(kbase + 8 + j) * 2048 + n0 + bcol]);
            char* base = (char*)lB + bcol * 128;
            *(ushort8*)(base + ((bkg * 64 + hh * 32)      ^ bsw)) = o0;
            *(ushort8*)(base + ((bkg * 64 + hh * 32 + 16) ^ bsw)) = o1;
        }
        __syncthreads();
        #pragma unroll
        for (int kk = 0; kk < 2; ++kk) {
            bf16x8 af[4], bv[4];
            #pragma unroll
            for (int m = 0; m < 4; ++m)
                af[m] = *(const bf16x8*)((const char*)lA +
                          (wr * 64 + m * 16 + lm) * 128 + (kk * 32 + lk) * 2);
            #pragma unroll
            for (int n = 0; n < 4; ++n) {
                int rr = wc * 64 + n * 16 + lm;
                bv[n] = *(const bf16x8*)((const char*)lB +
                          rr * 128 + (((kk * 32 + lk) * 2) ^ ((rr & 7) << 4)));
            }
            #pragma unroll
            for (int m = 0; m < 4; ++m)
                #pragma unroll
                for (int n = 0; n < 4; ++n)
                    acc[m][n] = __builtin_amdgcn_mfma_f32_16x16x32_bf16(
                        af[m], bv[n], acc[m][n], 0, 0, 0);
        }
        __syncthreads();
    }

    float* C = P + (size_t)blockIdx.z * 524288;
    const int rbase = m0 + wr * 64 + (lane >> 4) * 4;
    const int cbase = n0 + wc * 64 + lm;
    #pragma unroll
    for (int m = 0; m < 4; ++m)
        #pragma unroll
        for (int n = 0; n < 4; ++n)
            #pragma unroll
            for (int j = 0; j < 4; ++j)
                C[(size_t)(rbase + m * 16 + j) * 2048 + cbase + n * 16] = acc[m][n][j];
}

// ---------------- G6+G7 fused: gi/gh partials, B from f32 (N,K) row-major ---
__global__ __launch_bounds__(256) void gemm67f_kernel(
    const unsigned short* __restrict__ xb, const unsigned short* __restrict__ hb,
    const float* __restrict__ Wih, const float* __restrict__ Whh,
    float* __restrict__ pg)
{
    __shared__ unsigned short lA[8192];
    __shared__ unsigned short lB[8192];
    const int tid = threadIdx.x;
    const int lane = tid & 63, wave = tid >> 6;
    const int wr = wave >> 1, wc = wave & 1;
    const int g = blockIdx.z >> 2, s = blockIdx.z & 3;
    const unsigned short* A = g ? hb : xb;
    const float* Bf = g ? Whh : Wih;
    const int sA   = g ? 1024 : 2048;
    const int koff = g ? s * 256 : s * 512;
    const int nt   = g ? 4 : 8;                    // kLen/64
    const int m0 = blockIdx.y * 128, n0 = blockIdx.x * 128;
    const int srow = tid >> 3, schunk = tid & 7;
    const int lm = lane & 15, lk = (lane >> 4) * 8;
    const int bsw = (srow & 7) << 4;               // (row&7), rows srow+32i

    f32x4 acc[4][4];
    #pragma unroll
    for (int m = 0; m < 4; ++m)
        #pragma unroll
        for (int n = 0; n < 4; ++n) { f32x4 z = {0.f,0.f,0.f,0.f}; acc[m][n] = z; }

    const unsigned short* Ag = A  + (size_t)(m0 + srow) * sA + koff + schunk * 8;
    const float*          Bg = Bf + (size_t)(n0 + srow) * sA + koff + schunk * 8;
    char* lap = (char*)lA + tid * 16;

    for (int t = 0; t < nt; ++t) {
        #pragma unroll
        for (int i = 0; i < 4; ++i)
            gload16(Ag + (size_t)(32 * i) * sA + t * 64, lap + i * 4096);
        #pragma unroll
        for (int i = 0; i < 4; ++i) {
            const float* src = Bg + (size_t)(32 * i) * sA + t * 64;
            float4 v0 = *(const float4*)(src);
            float4 v1 = *(const float4*)(src + 4);
            ushort8 o;
            o[0] = f2bf(v0.x); o[1] = f2bf(v0.y); o[2] = f2bf(v0.z); o[3] = f2bf(v0.w);
            o[4] = f2bf(v1.x); o[5] = f2bf(v1.y); o[6] = f2bf(v1.z); o[7] = f2bf(v1.w);
            *(ushort8*)((char*)lB + (srow + 32 * i) * 128 + ((schunk * 16) ^ bsw)) = o;
        }
        __syncthreads();
        #pragma unroll
        for (int kk = 0; kk < 2; ++kk) {
            bf16x8 af[4], bv[4];
            #pragma unroll
            for (int m = 0; m < 4; ++m)
                af[m] = *(const bf16x8*)((const char*)lA +
                          (wr * 64 + m * 16 + lm) * 128 + (kk * 32 + lk) * 2);
            #pragma unroll
            for (int n = 0; n < 4; ++n) {
                int rr = wc * 64 + n * 16 + lm;
                bv[n] = *(const bf16x8*)((const char*)lB +
                          rr * 128 + (((kk * 32 + lk) * 2) ^ ((rr & 7) << 4)));
            }
            #pragma unroll
            for (int m = 0; m < 4; ++m)
                #pragma unroll
                for (int n = 0; n < 4; ++n)
                    acc[m][n] = __builtin_amdgcn_mfma_f32_16x16x32_bf16(
                        af[m], bv[n], acc[m][n], 0, 0, 0);
        }
        __syncthreads();
    }

    float* C = pg + (size_t)blockIdx.z * 786432;
    const int rbase = m0 + wr * 64 + (lane >> 4) * 4;
    const int cbase = n0 + wc * 64 + lm;
    #pragma unroll
    for (int m = 0; m < 4; ++m)
        #pragma unroll
        for (int n = 0; n < 4; ++n)
            #pragma unroll
            for (int j = 0; j < 4; ++j)
                C[(size_t)(rbase + m * 16 + j) * 3072 + cbase + n * 16] = acc[m][n][j];
}

// ---------------- G8 fused: logits = hnewb @ W_out(f32,(K,N)) + b_out -------
// 256x64 tile, 4 waves stacked on M, grid 500.
__global__ __launch_bounds__(256) void gemm8_kernel(
    const unsigned short* __restrict__ A, const float* __restrict__ Wout,
    const float* __restrict__ bias, float* __restrict__ C)
{
    __shared__ unsigned short lA0[16384]; __shared__ unsigned short lA1[16384];
    __shared__ unsigned short lB0[4096];  __shared__ unsigned short lB1[4096];
    const int tid  = threadIdx.x;
    const int lane = tid & 63, wave = tid >> 6;
    const int n0 = blockIdx.x * 64;
    const int lm = lane & 15, lk = (lane >> 4) * 8;
    const int srow = tid >> 3, schunk = tid & 7;      // A staging
    const int bcol = tid & 63, bkg = tid >> 6;        // B staging (col, k-grp)
    const int bsw  = (bcol & 7) << 4;                 // B LDS XOR swizzle

    f32x4 acc[4][4];
    #pragma unroll
    for (int m = 0; m < 4; ++m)
        #pragma unroll
        for (int n = 0; n < 4; ++n) { f32x4 z = {0.f,0.f,0.f,0.f}; acc[m][n] = z; }

    const unsigned short* Ag = A + (size_t)srow * 1024 + schunk * 8;

    auto stageA = [&](unsigned short* la_, int t) {
        char* la = (char*)la_ + tid * 16;
        #pragma unroll
        for (int i = 0; i < 8; ++i)
            gload16(Ag + (size_t)(32 * i) * 1024 + t * 64, la + i * 4096);
    };
    float bv_[16];
    auto loadB = [&](int t) {
        const float* src = Wout + (size_t)(t * 64 + bkg * 16) * 32000 + n0 + bcol;
        #pragma unroll
        for (int j = 0; j < 16; ++j) bv_[j] = src[(size_t)j * 32000];
    };
    auto writeB = [&](unsigned short* lb_) {
        ushort8 o0, o1;
        #pragma unroll
        for (int j = 0; j < 8; ++j) { o0[j] = f2bf(bv_[j]); o1[j] = f2bf(bv_[j + 8]); }
        char* base = (char*)lb_ + bcol * 128;
        *(ushort8*)(base + ((bkg * 32)      ^ bsw)) = o0;
        *(ushort8*)(base + ((bkg * 32 + 16) ^ bsw)) = o1;
    };
    auto compute = [&](const unsigned short* la_, const unsigned short* lb_) {
        #pragma unroll
        for (int kk = 0; kk < 2; ++kk) {
            bf16x8 af[4], bv[4];
            #pragma unroll
            for (int m = 0; m < 4; ++m)
                af[m] = *(const bf16x8*)((const char*)la_ +
                          (wave * 64 + m * 16 + lm) * 128 + (kk * 32 + lk) * 2);
            #pragma unroll
            for (int n = 0; n < 4; ++n) {
                int rr = n * 16 + lm;
                bv[n] = *(const bf16x8*)((const char*)lb_ +
                          rr * 128 + (((kk * 32 + lk) * 2) ^ ((rr & 7) << 4)));
            }
            #pragma unroll
            for (int m = 0; m < 4; ++m)
                #pragma unroll
                for (int n = 0; n < 4; ++n)
                    acc[m][n] = __builtin_amdgcn_mfma_f32_16x16x32_bf16(
                        af[m], bv[n], acc[m][n], 0, 0, 0);
        }
    };

    stageA(lA0, 0); loadB(0); writeB(lB0);
    __syncthreads();
    const int nt = 16;                                 // K=1024 / 64
    for (int t = 0; t < nt; t += 2) {
        if (t + 1 < nt) { stageA(lA1, t + 1); loadB(t + 1); }
        compute(lA0, lB0);
        if (t + 1 < nt) writeB(lB1);
        __syncthreads();
        if (t + 1 < nt) {
            if (t + 2 < nt) { stageA(lA0, t + 2); loadB(t + 2); }
            compute(lA1, lB1);
            if (t + 2 < nt) writeB(lB0);
            __syncthreads();
        }
    }

    const int rbase = wave * 64 + (lane >> 4) * 4;
    const int cbase = n0 + lm;
    #pragma unroll
    for (int m = 0; m < 4; ++m) {
        #pragma unroll
        for (int n = 0; n < 4; ++n) {
            int col = cbase + n * 16;
            float bvv = bias[col];
            #pragma unroll
            for (int j = 0; j < 4; ++j)
                C[(size_t)(rbase + m * 16 + j) * 32000 + col] = acc[m][n][j] + bvv;
        }
    }
}

// ---------------- G5 split-K16 reduce + bias -> bf16 x ----------------------
__global__ __launch_bounds__(256) void reduce5_kernel(
    const float* __restrict__ P, const float* __restrict__ bias,
    unsigned short* __restrict__ xb)
{
    int i = blockIdx.x * 256 + threadIdx.x;        // 131072 float4s
    const float4* p = (const float4*)P;
    float4 bb = ((const float4*)bias)[i & 511];
    float s0 = bb.x, s1 = bb.y, s2 = bb.z, s3 = bb.w;
    #pragma unroll
    for (int s = 0; s < 16; ++s) {
        float4 v = p[i + s * 131072];
        s0 += v.x; s1 += v.y; s2 += v.z; s3 += v.w;
    }
    ((ushort4*)xb)[i] = make_ushort4(f2bf(s0), f2bf(s1), f2bf(s2), f2bf(s3));
}

// ---------------- GRU pointwise + split-K reduce (gate order r,z,n) ---------
__global__ __launch_bounds__(256) void gru_kernel(
    const float* __restrict__ pg, const float* __restrict__ b_ih,
    const float* __restrict__ b_hh, const float* __restrict__ h,
    unsigned short* __restrict__ hnewb)
{
    int idx = blockIdx.x * 256 + threadIdx.x;       // 262144
    int b = idx >> 10, j = idx & 1023;
    float ir = b_ih[j], iz = b_ih[1024 + j], in_ = b_ih[2048 + j];
    float hr = b_hh[j], hz = b_hh[1024 + j], hn  = b_hh[2048 + j];
    #pragma unroll
    for (int s = 0; s < 4; ++s) {
        const float* gi = pg + (size_t)s * 786432 + (size_t)b * 3072;
        ir  += gi[j]; iz += gi[1024 + j]; in_ += gi[2048 + j];
        const float* gh = pg + (size_t)(4 + s) * 786432 + (size_t)b * 3072;
        hr  += gh[j]; hz += gh[1024 + j]; hn  += gh[2048 + j];
    }
    float r = 1.f / (1.f + expf(-(ir + hr)));
    float z = 1.f / (1.f + expf(-(iz + hz)));
    float n = tanhf(in_ + r * hn);
    hnewb[idx] = f2bf((1.f - z) * n + z * h[idx]);
}

// ---------------------------------------------------------------------------
extern "C" void kernel_launch(void* const* d_in, const int* in_sizes, int n_in,
                              void* d_out, int out_size, void* d_ws, size_t ws_size,
                              hipStream_t stream)
{
    const int*   input_ids    = (const int*)  d_in[0];
    const float* hidden       = (const float*)d_in[1];
    const float* enc_out      = (const float*)d_in[2];
    const int*   input_tensor = (const int*)  d_in[3];
    const int*   pairing_ids  = (const int*)  d_in[4];
    const float* emb_dec      = (const float*)d_in[5];
    const float* enc_emb      = (const float*)d_in[6];
    const float* Wq_i  = (const float*)d_in[7];
    const float* Wk_i  = (const float*)d_in[8];
    const float* wa_i  = (const float*)d_in[9];
    const float* Wq_p  = (const float*)d_in[10];
    const float* Wk_p  = (const float*)d_in[11];
    const float* wa_p  = (const float*)d_in[12];
    const float* ba_p  = (const float*)d_in[13];
    const float* W_lin = (const float*)d_in[14];
    const float* b_lin = (const float*)d_in[15];
    const float* W_ih  = (const float*)d_in[16];
    const float* W_hh  = (const float*)d_in[17];
    const float* b_ih  = (const float*)d_in[18];
    const float* b_hh  = (const float*)d_in[19];
    const float* W_out = (const float*)d_in[20];
    const float* b_out = (const float*)d_in[21];

    // ---- workspace layout (time-shared slots, lifetimes serial) ------------
    constexpr size_t OFF_HB    = 0;            // bf16 h, alive all
    constexpr size_t OFF_HNEW  = 524288;       // bf16 h_new, gru..G8
    constexpr size_t OFF_WQI   = 1048576;      // WqiT 2MB (..dual)
    constexpr size_t OFF_WQP   = 3145728;      // WqpT 2MB (..dual)
    constexpr size_t OFF_WKI   = 5242880;      // WkiT 4MB (..gemm24p3)
    constexpr size_t OFF_WKP   = 9437184;      // WkpT 4MB (..gemm24p3)
    constexpr size_t OFF_ENC   = 13631488;     // encb 21MB (..gemm24p3)
    constexpr size_t OFF_SLOT1 = 34603008;     // kp_all 10.5MB (..gather)
                                               //   -> outp/xb
    constexpr size_t OFF_SLOT2 = 55574528;     // encembb (..gemm24p3)
    constexpr size_t OFF_SCI   = 78643200;     // 24KB
    constexpr size_t OFF_SCP   = 78667776;     // 20KB
    constexpr size_t OFF_PGI   = 1048576;      // G67 partials 8x3MB=24MB
                                               //   ([1M,34.6M) free after gemm24p3)
    constexpr size_t NEED      = 79167488;
    if (ws_size < NEED) {
        fprintf(stderr, "kernel_launch: ws_size %zu < needed %zu\n", ws_size, NEED);
        return;
    }
    char* ws = (char*)d_ws;
    unsigned short* hb     = (unsigned short*)(ws + OFF_HB);
    unsigned short* hnewb  = (unsigned short*)(ws + OFF_HNEW);
    unsigned short* WqiT   = (unsigned short*)(ws + OFF_WQI);
    unsigned short* WqpT   = (unsigned short*)(ws + OFF_WQP);
    unsigned short* WkiT   = (unsigned short*)(ws + OFF_WKI);
    unsigned short* WkpT   = (unsigned short*)(ws + OFF_WKP);
    unsigned short* encb   = (unsigned short*)(ws + OFF_ENC);
    unsigned short* kp_all = (unsigned short*)(ws + OFF_SLOT1);
    unsigned short* encembb= (unsigned short*)(ws + OFF_SLOT2);
    unsigned short* outp   = (unsigned short*)(ws + OFF_SLOT1);          // after gather
    unsigned short* xb     = (unsigned short*)(ws + OFF_SLOT1 + 18350080);  // 1MB
    float*          sc_i   = (float*)         (ws + OFF_SCI);
    float*          sc_p   = (float*)         (ws + OFF_SCP);
    float*          pgi    = (float*)         (ws + OFF_PGI);
    // d_out (32.77MB) scratch until gemm8 overwrites it:
    //   key [0,10.5MB); pqQ [21,25.2MB); pqP [25.2,29.4MB); then pG5 [0,32MB)
    unsigned short* key    = (unsigned short*)d_out;
    float*          pqQ    = (float*)((char*)d_out + 20971520);
    float*          pqP    = (float*)((char*)d_out + 20971520 + 4194304);
    float*          pG5    = (float*)d_out;

    // 1. prep1: all converts + Wq/Wk transposes (one launch)
    prep1_kernel<<<22032, 256, 0, stream>>>(hidden, enc_out, enc_emb,
                                            Wq_i, Wq_p, Wk_i, Wk_p,
                                            hb, encb, encembb,
                                            WqiT, WqpT, WkiT, WkpT);

    // 2. dual split-K4: q partials -> d_out tail (reduce folded into scores)
    gemm_dual_kernel<<<dim3(8, 2, 8), 256, 0, stream>>>(hb, WqiT, WqpT, pqQ, pqP);

    // 3. gemm24p3 (full-K, 3-deep counted-vmcnt, XCD remap): kp_all, key
    gemm24p3_kernel<<<640, 256, 0, stream>>>(encembb, encb, WkpT, WkiT,
                                             kp_all, key);

    // 4-5. ingredient scores (q-reduce folded); pairing scores (qp-reduce folded)
    attn_scores_q_kernel<<<5120, 256, 0, stream>>>(pqQ, key, wa_i, sc_i);
    attn_scores_gather_q_kernel<<<5120, 256, 0, stream>>>(pqP, kp_all, wa_p, ba_p,
                                                          sc_i, input_tensor,
                                                          pairing_ids, sc_p);

    // 6. out_pair = [emb | softmax(s)*s @ enc_emb-gather]  (overwrites kp_all)
    out_pair_kernel<<<1536, 256, 0, stream>>>(sc_p, enc_emb, sc_i, input_tensor,
                                              pairing_ids, emb_dec, input_ids, outp);

    // 7-8. G5 fused (W_lin f32 in-GEMM): split-K16 -> partials in d_out -> xb
    gemm5f_kernel<<<dim3(16, 2, 16), 256, 0, stream>>>(outp, W_lin, pG5);
    reduce5_kernel<<<512, 256, 0, stream>>>(pG5, b_lin, xb);

    // 9. G6+G7 fused (W_ih/W_hh f32 in-GEMM), split-K4 each
    gemm67f_kernel<<<dim3(24, 2, 8), 256, 0, stream>>>(xb, hb, W_ih, W_hh, pgi);

    // 10. GRU pointwise (+ split-K reduce + biases) -> h_new bf16
    gru_kernel<<<1024, 256, 0, stream>>>(pgi, b_ih, b_hh, hidden, hnewb);

    // 11. G8 fused: logits = h_new @ W_out + b_out (overwrites d_out scratch)
    gemm8_kernel<<<500, 256, 0, stream>>>(hnewb, W_out, b_out, (float*)d_out);
}

// Round 17
// 220.411 us; speedup vs baseline: 1.0603x; 1.0603x over previous
//
#include <hip/hip_runtime.h>
#include <cstdio>

// ---------------------------------------------------------------------------
// PairAttnDecoderRNN forward, MI355X/gfx950.  Round 17 = Round 15 (best,
// 220.6us) reverted exactly. r16 post-mortem: full-K+3-deep cut FETCH to the
// 53MB ideal but LDS 48KB halved occupancy (5->2.5 blk/CU) and TLP loss beat
// ILP gain (m132 trade confirmed on this shape). The r15 point - split-K2,
// BK=32 2-deep counted-vmcnt (T4), XCD remap (T1), 32KB LDS @ 5 blk/CU,
// grid 1280 = one full dispatch round - is the measured local optimum.
// 11 launches.
// ---------------------------------------------------------------------------

using f32x4   = __attribute__((ext_vector_type(4))) float;
using bf16x8  = __attribute__((ext_vector_type(8))) short;
using ushort8 = __attribute__((ext_vector_type(8))) unsigned short;

__device__ __forceinline__ unsigned short f2bf(float x) {
    unsigned u = __builtin_bit_cast(unsigned, x);
    u += 0x7fffu + ((u >> 16) & 1u);          // RNE
    return (unsigned short)(u >> 16);
}
__device__ __forceinline__ float bf2f(unsigned short u) {
    return __builtin_bit_cast(float, ((unsigned)u) << 16);
}

// async global->LDS, 16B per lane. LDS dest = wave-uniform base + lane*16.
__device__ __forceinline__ void gload16(const void* g, void* l) {
    auto gp = (const __attribute__((address_space(1))) void*)g;
    auto lp = (__attribute__((address_space(3))) void*)l;
    __builtin_amdgcn_global_load_lds(gp, lp, 16, 0, 0);
}

// ---------------- (R,C) fp32 -> (C,R) bf16 transpose body, 128r x 32c tile --
__device__ __forceinline__ void transpose_body(
    const float* __restrict__ in, unsigned short* __restrict__ out,
    int R, int C, int r0, int c0)
{
    __shared__ float t[32][129];
    const int tid = threadIdx.x;
    const int lr = tid >> 3;              // 0..31
    const int cc = (tid & 7) * 4;         // col chunk
    #pragma unroll
    for (int i = 0; i < 4; ++i) {
        int r = lr + 32 * i;
        float4 v = *(const float4*)(in + (size_t)(r0 + r) * C + c0 + cc);
        t[cc + 0][r] = v.x; t[cc + 1][r] = v.y;
        t[cc + 2][r] = v.z; t[cc + 3][r] = v.w;
    }
    __syncthreads();
    const int rc = (tid & 15) * 8;        // r chunk (8 outputs = 16B store)
    #pragma unroll
    for (int p = 0; p < 2; ++p) {
        int c = (tid >> 4) + 16 * p;
        const float* src = &t[c][rc];
        ushort8 o;
        #pragma unroll
        for (int j = 0; j < 8; ++j) o[j] = f2bf(src[j]);
        *(ushort8*)(out + (size_t)(c0 + c) * R + r0 + rc) = o;
    }
}

// ---------------- prep1: all input converts + Wq/Wk transposes --------------
__global__ __launch_bounds__(256) void prep1_kernel(
    const float* __restrict__ hidden, const float* __restrict__ enc_out,
    const float* __restrict__ enc_emb,
    const float* __restrict__ Wq_i, const float* __restrict__ Wq_p,
    const float* __restrict__ Wk_i, const float* __restrict__ Wk_p,
    unsigned short* __restrict__ hb, unsigned short* __restrict__ encb,
    unsigned short* __restrict__ encembb,
    unsigned short* __restrict__ WqiT, unsigned short* __restrict__ WqpT,
    unsigned short* __restrict__ WkiT, unsigned short* __restrict__ WkpT)
{
    const int bid = blockIdx.x;
    if (bid < 20496) {
        int i = bid * 256 + threadIdx.x;   // total 5,246,976 quads
        const float* src; unsigned short* dst; int j;
        if (i < 65536)        { src = hidden;  dst = hb;      j = i; }
        else if (i < 2686976) { src = enc_out; dst = encb;    j = i - 65536; }
        else                  { src = enc_emb; dst = encembb; j = i - 2686976; }
        float4 v = ((const float4*)src)[j];
        ((ushort4*)dst)[j] = make_ushort4(f2bf(v.x), f2bf(v.y), f2bf(v.z), f2bf(v.w));
    } else if (bid < 21008) {
        int local = bid - 20496;           // 512: z(2) x by(8) x bx(32)
        int bz = local >> 8, rem = local & 255;
        transpose_body(bz ? Wq_p : Wq_i, bz ? WqpT : WqiT,
                       1024, 1024, (rem >> 5) * 128, (rem & 31) * 32);
    } else {
        int local = bid - 21008;           // 1024: z(2) x by(16) x bx(32)
        int bz = local >> 9, rem = local & 511;
        transpose_body(bz ? Wk_p : Wk_i, bz ? WkpT : WkiT,
                       2048, 1024, (rem >> 5) * 128, (rem & 31) * 32);
    }
}

// ---------------- bf16 MFMA GEMM core: C(M,N) = A(M,K) * Bt(N,K)^T ----------
// 128x128 tile, BK=64, 4 waves 2x2, 16x16x32 MFMA, global_load_lds width=16.
// SINGLE-buffered 32KB LDS (m97 structure): {stage; bar; compute; bar}.
template<int OUTBF, bool HAS_BIAS>
__device__ __forceinline__ void gemm_core(
    const unsigned short* __restrict__ A, const unsigned short* __restrict__ Bt,
    const float* __restrict__ bias, void* __restrict__ Cout, int Ncols,
    int sA, int sB, int kLen, int m0, int n0,
    unsigned short* lA, unsigned short* lB)
{
    const int tid = threadIdx.x;
    const int lane = tid & 63, wave = tid >> 6;
    const int wr = wave >> 1, wc = wave & 1;
    const int srow = tid >> 3, schunk = tid & 7;
    const int lm = lane & 15, lk = (lane >> 4) * 8;

    f32x4 acc[4][4];
    #pragma unroll
    for (int m = 0; m < 4; ++m)
        #pragma unroll
        for (int n = 0; n < 4; ++n) { f32x4 z = {0.f,0.f,0.f,0.f}; acc[m][n] = z; }

    const unsigned short* Ag = A  + (size_t)(m0 + srow) * sA + schunk * 8;
    const unsigned short* Bg = Bt + (size_t)(n0 + srow) * sB + schunk * 8;
    const int nt = kLen >> 6;

    char* lap = (char*)lA + tid * 16;
    char* lbp = (char*)lB + tid * 16;

    for (int t = 0; t < nt; ++t) {
        #pragma unroll
        for (int i = 0; i < 4; ++i) {
            gload16(Ag + (size_t)(32 * i) * sA + t * 64, lap + i * 4096);
            gload16(Bg + (size_t)(32 * i) * sB + t * 64, lbp + i * 4096);
        }
        __syncthreads();
        #pragma unroll
        for (int kk = 0; kk < 2; ++kk) {
            bf16x8 af[4], bv[4];
            #pragma unroll
            for (int m = 0; m < 4; ++m)
                af[m] = *(const bf16x8*)((const char*)lA +
                          (wr * 64 + m * 16 + lm) * 128 + (kk * 32 + lk) * 2);
            #pragma unroll
            for (int n = 0; n < 4; ++n)
                bv[n] = *(const bf16x8*)((const char*)lB +
                          (wc * 64 + n * 16 + lm) * 128 + (kk * 32 + lk) * 2);
            #pragma unroll
            for (int m = 0; m < 4; ++m)
                #pragma unroll
                for (int n = 0; n < 4; ++n)
                    acc[m][n] = __builtin_amdgcn_mfma_f32_16x16x32_bf16(
                        af[m], bv[n], acc[m][n], 0, 0, 0);
        }
        __syncthreads();
    }

    // epilogue: C/D layout col=lane&15, row=(lane>>4)*4+j  [m89/m91 verified]
    const int rbase = m0 + wr * 64 + (lane >> 4) * 4;
    const int cbase = n0 + wc * 64 + lm;
    #pragma unroll
    for (int m = 0; m < 4; ++m) {
        #pragma unroll
        for (int n = 0; n < 4; ++n) {
            int col = cbase + n * 16;
            float bvv = HAS_BIAS ? bias[col] : 0.0f;
            #pragma unroll
            for (int j = 0; j < 4; ++j) {
                int row = rbase + m * 16 + j;
                float v = acc[m][n][j] + bvv;
                if (OUTBF)
                    ((unsigned short*)Cout)[(size_t)row * Ncols + col] = f2bf(v);
                else
                    ((float*)Cout)[(size_t)row * Ncols + col] = v;
            }
        }
    }
}

#define GEMM_SHARED \
    __shared__ unsigned short lA[8192]; __shared__ unsigned short lB[8192];

// G1+G3 merged, split-K4: z = g*4+s; partials f32 -> P{g} + s*262144
__global__ __launch_bounds__(256) void gemm_dual_kernel(
    const unsigned short* A, const unsigned short* B0, const unsigned short* B1,
    float* P0, float* P1)
{
    GEMM_SHARED
    const int g = blockIdx.z >> 2, s = blockIdx.z & 3;
    const unsigned short* Bt = (g ? B1 : B0) + s * 256;
    float* C = (g ? P1 : P0) + (size_t)s * 262144;
    gemm_core<0,false>(A + s * 256, Bt, nullptr, C, 1024, 1024, 1024, 256,
                       blockIdx.y * 128, blockIdx.x * 128, lA, lB);
}

// ---------------- gemm24p: G4'+G2 merged, split-K2, BK=32 dbuf --------------
// COUNTED-VMCNT pipeline (T4) + XCD-aware bijective remap (T1):
// 1D grid 1280; xcd=w&7 owns z=xcd>>1 and 20 contiguous A-panels x all 8 bx
// -> A-panel (512KB) L2-private per XCD; 2-deep pipeline covers L2 latency.
__global__ __launch_bounds__(256) void gemm24p_kernel(
    const unsigned short* encembb, const unsigned short* encb,
    const unsigned short* WkpT, const unsigned short* WkiT,
    unsigned short* kpP, unsigned short* keyP, size_t pStride)
{
    __shared__ unsigned short lA0[4096]; __shared__ unsigned short lA1[4096];
    __shared__ unsigned short lB0[4096]; __shared__ unsigned short lB1[4096];
    // XCD remap: w -> (z, by, bx), bijective over 1280 = 8 XCD x 160
    const int w   = (int)blockIdx.x;
    const int xcd = w & 7;
    const int r   = w >> 3;                   // 0..159
    const int z   = xcd >> 1;                 // 0..3
    const int by  = (xcd & 1) * 20 + (r >> 3);// 0..39
    const int bx  = r & 7;                    // 0..7
    const int g = z >> 1, h = z & 1;
    const unsigned short* A  = (g ? encb : encembb) + h * 1024;
    const unsigned short* Bt = (g ? WkiT : WkpT)    + h * 1024;
    unsigned short* Cb = (g ? keyP : kpP) + (size_t)h * pStride;
    const int m0 = by * 128, n0 = bx * 128;
    const int tid = threadIdx.x;
    const int lane = tid & 63, wave = tid >> 6;
    const int wr = wave >> 1, wc = wave & 1;
    const int lm = lane & 15;
    const int q  = lane >> 4;                 // k-chunk 0..3 (8 elems each)
    const int srow = tid >> 2;                // 0..63 (also +64 for 2nd gload)
    const int sc   = (tid & 3) ^ (srow & 3);  // pre-swizzled global chunk

    f32x4 acc[4][4];
    #pragma unroll
    for (int m = 0; m < 4; ++m)
        #pragma unroll
        for (int n = 0; n < 4; ++n) { f32x4 zz = {0.f,0.f,0.f,0.f}; acc[m][n] = zz; }

    const unsigned short* Ag = A  + (size_t)(m0 + srow) * 2048 + sc * 8;
    const unsigned short* Bg = Bt + (size_t)(n0 + srow) * 2048 + sc * 8;

    auto stage = [&](unsigned short* la_, unsigned short* lb_, int t) {
        char* pa = (char*)la_ + tid * 16;
        char* pb = (char*)lb_ + tid * 16;
        gload16(Ag + t * 32, pa);
        gload16(Ag + (size_t)64 * 2048 + t * 32, pa + 4096);
        gload16(Bg + t * 32, pb);
        gload16(Bg + (size_t)64 * 2048 + t * 32, pb + 4096);
    };
    auto compute = [&](const unsigned short* la_, const unsigned short* lb_) {
        bf16x8 af[4], bv[4];
        #pragma unroll
        for (int m = 0; m < 4; ++m) {
            int rr = wr * 64 + m * 16 + lm;
            af[m] = *(const bf16x8*)((const char*)la_ + rr * 64 + ((q ^ (rr & 3)) * 16));
        }
        #pragma unroll
        for (int n = 0; n < 4; ++n) {
            int rr = wc * 64 + n * 16 + lm;
            bv[n] = *(const bf16x8*)((const char*)lb_ + rr * 64 + ((q ^ (rr & 3)) * 16));
        }
        #pragma unroll
        for (int m = 0; m < 4; ++m)
            #pragma unroll
            for (int n = 0; n < 4; ++n)
                acc[m][n] = __builtin_amdgcn_mfma_f32_16x16x32_bf16(
                    af[m], bv[n], acc[m][n], 0, 0, 0);
    };

    // prologue: tiles 0 and 1 in flight; wait only for tile 0 (oldest 4).
    stage(lA0, lB0, 0);                                   // 4 outstanding
    stage(lA1, lB1, 1);                                   // 8 outstanding
    asm volatile("s_waitcnt vmcnt(4)" ::: "memory");      // tile-0 loads done
    __builtin_amdgcn_s_barrier();
    __builtin_amdgcn_sched_barrier(0);

    // main loop: computes tiles 0..29, stages tiles 2..31 (kLen=1024 -> 32).
    for (int t = 0; t < 30; t += 2) {
        compute(lA0, lB0);                                // tile t
        __builtin_amdgcn_s_barrier();                     // WAR: done reading b0
        __builtin_amdgcn_sched_barrier(0);
        stage(lA0, lB0, t + 2);                           // outstanding: 8
        asm volatile("s_waitcnt vmcnt(4)" ::: "memory");  // tile t+1 done
        __builtin_amdgcn_s_barrier();                     // b1 ready block-wide
        __builtin_amdgcn_sched_barrier(0);

        compute(lA1, lB1);                                // tile t+1
        __builtin_amdgcn_s_barrier();                     // WAR: done reading b1
        __builtin_amdgcn_sched_barrier(0);
        stage(lA1, lB1, t + 3);                           // outstanding: 8
        asm volatile("s_waitcnt vmcnt(4)" ::: "memory");  // tile t+2 done
        __builtin_amdgcn_s_barrier();                     // b0 ready block-wide
        __builtin_amdgcn_sched_barrier(0);
    }
    // tail: tile 30 ready in b0 (waited in last loop half); tile 31 in flight.
    compute(lA0, lB0);                                    // tile 30
    asm volatile("s_waitcnt vmcnt(0)" ::: "memory");      // tile-31 loads done
    __builtin_amdgcn_s_barrier();
    __builtin_amdgcn_sched_barrier(0);
    compute(lA1, lB1);                                    // tile 31

    // epilogue: C/D layout col=lane&15, row=(lane>>4)*4+j
    const int rbase = m0 + wr * 64 + q * 4;
    const int cbase = n0 + wc * 64 + lm;
    #pragma unroll
    for (int m = 0; m < 4; ++m)
        #pragma unroll
        for (int n = 0; n < 4; ++n)
            #pragma unroll
            for (int j = 0; j < 4; ++j)
                Cb[(size_t)(rbase + m * 16 + j) * 1024 + cbase + n * 16] =
                    f2bf(acc[m][n][j]);
}

// ---------------- ingredient scores: q = sum of 4 pqQ slices, key pair ------
__global__ __launch_bounds__(256) void attn_scores2q_kernel(
    const float* __restrict__ pqQ, const unsigned short* __restrict__ kP,
    size_t kStride, const float* __restrict__ wa, float* __restrict__ scores)
{
    const int bm = blockIdx.x;          // b*20 + m
    const int b  = bm / 20;
    const int tid = threadIdx.x;
    float4 qa = ((const float4*)(pqQ + (size_t)b * 1024))[tid];
    float4 qb = ((const float4*)(pqQ + 262144 + (size_t)b * 1024))[tid];
    float4 qc = ((const float4*)(pqQ + 524288 + (size_t)b * 1024))[tid];
    float4 qd = ((const float4*)(pqQ + 786432 + (size_t)b * 1024))[tid];
    float4 qv = make_float4(qa.x + qb.x + qc.x + qd.x, qa.y + qb.y + qc.y + qd.y,
                            qa.z + qb.z + qc.z + qd.z, qa.w + qb.w + qc.w + qd.w);
    ushort4 k0 = ((const ushort4*)(kP + (size_t)bm * 1024))[tid];
    ushort4 k1 = ((const ushort4*)(kP + kStride + (size_t)bm * 1024))[tid];
    float4 wv  = ((const float4*)wa)[tid];
    float p = tanhf(qv.x + bf2f(k0.x) + bf2f(k1.x)) * wv.x
            + tanhf(qv.y + bf2f(k0.y) + bf2f(k1.y)) * wv.y
            + tanhf(qv.z + bf2f(k0.z) + bf2f(k1.z)) * wv.z
            + tanhf(qv.w + bf2f(k0.w) + bf2f(k1.w)) * wv.w;
    #pragma unroll
    for (int off = 32; off > 0; off >>= 1) p += __shfl_down(p, off);
    __shared__ float sp[4];
    if ((tid & 63) == 0) sp[tid >> 6] = p;
    __syncthreads();
    if (tid == 0) scores[bm] = sp[0] + sp[1] + sp[2] + sp[3];
}

// argmax over ingredient scores (first-max tiebreak = jnp) -> ingredient id
__device__ __forceinline__ int argmax_ing(
    const float* __restrict__ sc_i, const int* __restrict__ input_tensor, int b)
{
    float best = sc_i[b * 20]; int bi = 0;
    #pragma unroll
    for (int m = 1; m < 20; ++m) {
        float v = sc_i[b * 20 + m];
        if (v > best) { best = v; bi = m; }
    }
    return input_tensor[b * 20 + bi];
}

// ---------------- pairing scores: q_p from 4 pqP slices; gather kpP pair ----
__global__ __launch_bounds__(256) void attn_scores_gather2q_kernel(
    const float* __restrict__ pqP, const unsigned short* __restrict__ kP,
    size_t kStride, const float* __restrict__ wa, const float* __restrict__ ba,
    const float* __restrict__ sc_i, const int* __restrict__ input_tensor,
    const int* __restrict__ pairing_ids, float* __restrict__ scores)
{
    const int bm = blockIdx.x;          // b*20 + k
    const int b  = bm / 20;
    const int kk = bm - b * 20;
    const int tid = threadIdx.x;
    const int ing = argmax_ing(sc_i, input_tensor, b);
    const int cid = pairing_ids[ing * 20 + kk];
    float4 qa = ((const float4*)(pqP + (size_t)b * 1024))[tid];
    float4 qb = ((const float4*)(pqP + 262144 + (size_t)b * 1024))[tid];
    float4 qc = ((const float4*)(pqP + 524288 + (size_t)b * 1024))[tid];
    float4 qd = ((const float4*)(pqP + 786432 + (size_t)b * 1024))[tid];
    float4 qv = make_float4(qa.x + qb.x + qc.x + qd.x, qa.y + qb.y + qc.y + qd.y,
                            qa.z + qb.z + qc.z + qd.z, qa.w + qb.w + qc.w + qd.w);
    ushort4 k0 = ((const ushort4*)(kP + (size_t)cid * 1024))[tid];
    ushort4 k1 = ((const ushort4*)(kP + kStride + (size_t)cid * 1024))[tid];
    float4 wv  = ((const float4*)wa)[tid];
    float p = tanhf(qv.x + bf2f(k0.x) + bf2f(k1.x)) * wv.x
            + tanhf(qv.y + bf2f(k0.y) + bf2f(k1.y)) * wv.y
            + tanhf(qv.z + bf2f(k0.z) + bf2f(k1.z)) * wv.z
            + tanhf(qv.w + bf2f(k0.w) + bf2f(k1.w)) * wv.w;
    #pragma unroll
    for (int off = 32; off > 0; off >>= 1) p += __shfl_down(p, off);
    __shared__ float sp[4];
    if ((tid & 63) == 0) sp[tid >> 6] = p;
    __syncthreads();
    if (tid == 0) scores[bm] = sp[0] + sp[1] + sp[2] + sp[3] + ba[0];
}

// ---------------- out_pair assembly (softmax*s + enc_emb gather folded) -----
__global__ __launch_bounds__(256) void out_pair_kernel(
    const float* __restrict__ s_p, const float* __restrict__ enc_emb,
    const float* __restrict__ sc_i, const int* __restrict__ input_tensor,
    const int* __restrict__ pairing_ids,
    const float* __restrict__ emb_dec, const int* __restrict__ input_ids,
    unsigned short* __restrict__ out_pairb)
{
    const int b = blockIdx.x / 6, seg = blockIdx.x % 6;
    const int tid = threadIdx.x;
    const int d = seg * 512 + tid * 2;
    ushort2 o;
    if (seg < 2) {                       // emb part, d < 1024
        float2 v = *(const float2*)(emb_dec + (size_t)input_ids[b] * 1024 + d);
        o.x = f2bf(v.x); o.y = f2bf(v.y);
    } else {                             // attn_app part: gather enc_emb f32
        const int ing = argmax_ing(sc_i, input_tensor, b);
        __shared__ float s_raw[20];
        if (tid < 20) s_raw[tid] = s_p[b * 20 + tid];
        __syncthreads();
        float mx = -1e30f;
        #pragma unroll
        for (int m = 0; m < 20; ++m) mx = fmaxf(mx, s_raw[m]);
        float den = 0.f; float w[20];
        #pragma unroll
        for (int m = 0; m < 20; ++m) { w[m] = expf(s_raw[m] - mx); den += w[m]; }
        const float inv = 1.f / den;
        const int dd = d - 1024;
        float a0 = 0.f, a1 = 0.f;
        #pragma unroll
        for (int k = 0; k < 20; ++k) {
            const int cid = pairing_ids[ing * 20 + k];
            float2 v = *(const float2*)(enc_emb + (size_t)cid * 2048 + dd);
            float a = w[k] * inv * s_raw[k];           // softmax * raw score
            a0 += a * v.x; a1 += a * v.y;
        }
        o.x = f2bf(a0); o.y = f2bf(a1);
    }
    *(ushort2*)(out_pairb + (size_t)b * 3072 + d) = o;
}

// ---------------- G5 fused: x-partials = out_pair @ W_lin^T (W_lin f32) -----
// split-K16: z in [0,16), kLen 192 (3 tiles). Partials -> d_out scratch.
__global__ __launch_bounds__(256) void gemm5f_kernel(
    const unsigned short* __restrict__ A, const float* __restrict__ Wlin,
    float* __restrict__ P)
{
    __shared__ unsigned short lA[8192];
    __shared__ unsigned short lB[8192];
    const int tid = threadIdx.x;
    const int lane = tid & 63, wave = tid >> 6;
    const int wr = wave >> 1, wc = wave & 1;
    const int m0 = blockIdx.y * 128, n0 = blockIdx.x * 128;
    const int koff = blockIdx.z * 192;
    const int srow = tid >> 3, schunk = tid & 7;
    const int lm = lane & 15, lk = (lane >> 4) * 8;
    const int bcol = tid & 127, bkg = tid >> 7;    // B: col 0..127, k-half 0..1
    const int bsw  = (bcol & 7) << 4;

    f32x4 acc[4][4];
    #pragma unroll
    for (int m = 0; m < 4; ++m)
        #pragma unroll
        for (int n = 0; n < 4; ++n) { f32x4 z = {0.f,0.f,0.f,0.f}; acc[m][n] = z; }

    const unsigned short* Ag = A + (size_t)(m0 + srow) * 3072 + koff + schunk * 8;
    char* lap = (char*)lA + tid * 16;

    for (int t = 0; t < 3; ++t) {
        #pragma unroll
        for (int i = 0; i < 4; ++i)
            gload16(Ag + (size_t)(32 * i) * 3072 + t * 64, lap + i * 4096);
        #pragma unroll
        for (int hh = 0; hh < 2; ++hh) {
            const int kbase = koff + t * 64 + bkg * 32 + hh * 16;
            ushort8 o0, o1;
            #pragma unroll
            for (int j = 0; j < 8; ++j)
                o0[j] = f2bf(Wlin[(size_t)(kbase + j) * 2048 + n0 + bcol]);
            #pragma unroll
            for (int j = 0; j < 8; ++j)
                o1[j] = f2bf(Wlin[(size_t)(kbase + 8 + j) * 2048 + n0 + bcol]);
            char* base = (char*)lB + bcol * 128;
            *(ushort8*)(base + ((bkg * 64 + hh * 32)      ^ bsw)) = o0;
            *(ushort8*)(base + ((bkg * 64 + hh * 32 + 16) ^ bsw)) = o1;
        }
        __syncthreads();
        #pragma unroll
        for (int kk = 0; kk < 2; ++kk) {
            bf16x8 af[4], bv[4];
            #pragma unroll
            for (int m = 0; m < 4; ++m)
                af[m] = *(const bf16x8*)((const char*)lA +
                          (wr * 64 + m * 16 + lm) * 128 + (kk * 32 + lk) * 2);
            #pragma unroll
            for (int n = 0; n < 4; ++n) {
                int rr = wc * 64 + n * 16 + lm;
                bv[n] = *(const bf16x8*)((const char*)lB +
                          rr * 128 + (((kk * 32 + lk) * 2) ^ ((rr & 7) << 4)));
            }
            #pragma unroll
            for (int m = 0; m < 4; ++m)
                #pragma unroll
                for (int n = 0; n < 4; ++n)
                    acc[m][n] = __builtin_amdgcn_mfma_f32_16x16x32_bf16(
                        af[m], bv[n], acc[m][n], 0, 0, 0);
        }
        __syncthreads();
    }

    float* C = P + (size_t)blockIdx.z * 524288;
    const int rbase = m0 + wr * 64 + (lane >> 4) * 4;
    const int cbase = n0 + wc * 64 + lm;
    #pragma unroll
    for (int m = 0; m < 4; ++m)
        #pragma unroll
        for (int n = 0; n < 4; ++n)
            #pragma unroll
            for (int j = 0; j < 4; ++j)
                C[(size_t)(rbase + m * 16 + j) * 2048 + cbase + n * 16] = acc[m][n][j];
}

// ---------------- G6+G7 fused: gi/gh partials, B from f32 (N,K) row-major ---
__global__ __launch_bounds__(256) void gemm67f_kernel(
    const unsigned short* __restrict__ xb, const unsigned short* __restrict__ hb,
    const float* __restrict__ Wih, const float* __restrict__ Whh,
    float* __restrict__ pg)
{
    __shared__ unsigned short lA[8192];
    __shared__ unsigned short lB[8192];
    const int tid = threadIdx.x;
    const int lane = tid & 63, wave = tid >> 6;
    const int wr = wave >> 1, wc = wave & 1;
    const int g = blockIdx.z >> 2, s = blockIdx.z & 3;
    const unsigned short* A = g ? hb : xb;
    const float* Bf = g ? Whh : Wih;
    const int sA   = g ? 1024 : 2048;
    const int koff = g ? s * 256 : s * 512;
    const int nt   = g ? 4 : 8;                    // kLen/64
    const int m0 = blockIdx.y * 128, n0 = blockIdx.x * 128;
    const int srow = tid >> 3, schunk = tid & 7;
    const int lm = lane & 15, lk = (lane >> 4) * 8;
    const int bsw = (srow & 7) << 4;               // (row&7), rows srow+32i

    f32x4 acc[4][4];
    #pragma unroll
    for (int m = 0; m < 4; ++m)
        #pragma unroll
        for (int n = 0; n < 4; ++n) { f32x4 z = {0.f,0.f,0.f,0.f}; acc[m][n] = z; }

    const unsigned short* Ag = A  + (size_t)(m0 + srow) * sA + koff + schunk * 8;
    const float*          Bg = Bf + (size_t)(n0 + srow) * sA + koff + schunk * 8;
    char* lap = (char*)lA + tid * 16;

    for (int t = 0; t < nt; ++t) {
        #pragma unroll
        for (int i = 0; i < 4; ++i)
            gload16(Ag + (size_t)(32 * i) * sA + t * 64, lap + i * 4096);
        #pragma unroll
        for (int i = 0; i < 4; ++i) {
            const float* src = Bg + (size_t)(32 * i) * sA + t * 64;
            float4 v0 = *(const float4*)(src);
            float4 v1 = *(const float4*)(src + 4);
            ushort8 o;
            o[0] = f2bf(v0.x); o[1] = f2bf(v0.y); o[2] = f2bf(v0.z); o[3] = f2bf(v0.w);
            o[4] = f2bf(v1.x); o[5] = f2bf(v1.y); o[6] = f2bf(v1.z); o[7] = f2bf(v1.w);
            *(ushort8*)((char*)lB + (srow + 32 * i) * 128 + ((schunk * 16) ^ bsw)) = o;
        }
        __syncthreads();
        #pragma unroll
        for (int kk = 0; kk < 2; ++kk) {
            bf16x8 af[4], bv[4];
            #pragma unroll
            for (int m = 0; m < 4; ++m)
                af[m] = *(const bf16x8*)((const char*)lA +
                          (wr * 64 + m * 16 + lm) * 128 + (kk * 32 + lk) * 2);
            #pragma unroll
            for (int n = 0; n < 4; ++n) {
                int rr = wc * 64 + n * 16 + lm;
                bv[n] = *(const bf16x8*)((const char*)lB +
                          rr * 128 + (((kk * 32 + lk) * 2) ^ ((rr & 7) << 4)));
            }
            #pragma unroll
            for (int m = 0; m < 4; ++m)
                #pragma unroll
                for (int n = 0; n < 4; ++n)
                    acc[m][n] = __builtin_amdgcn_mfma_f32_16x16x32_bf16(
                        af[m], bv[n], acc[m][n], 0, 0, 0);
        }
        __syncthreads();
    }

    float* C = pg + (size_t)blockIdx.z * 786432;
    const int rbase = m0 + wr * 64 + (lane >> 4) * 4;
    const int cbase = n0 + wc * 64 + lm;
    #pragma unroll
    for (int m = 0; m < 4; ++m)
        #pragma unroll
        for (int n = 0; n < 4; ++n)
            #pragma unroll
            for (int j = 0; j < 4; ++j)
                C[(size_t)(rbase + m * 16 + j) * 3072 + cbase + n * 16] = acc[m][n][j];
}

// ---------------- G8 fused: logits = hnewb @ W_out(f32,(K,N)) + b_out -------
// 256x64 tile, 4 waves stacked on M, grid 500.
__global__ __launch_bounds__(256) void gemm8_kernel(
    const unsigned short* __restrict__ A, const float* __restrict__ Wout,
    const float* __restrict__ bias, float* __restrict__ C)
{
    __shared__ unsigned short lA0[16384]; __shared__ unsigned short lA1[16384];
    __shared__ unsigned short lB0[4096];  __shared__ unsigned short lB1[4096];
    const int tid  = threadIdx.x;
    const int lane = tid & 63, wave = tid >> 6;
    const int n0 = blockIdx.x * 64;
    const int lm = lane & 15, lk = (lane >> 4) * 8;
    const int srow = tid >> 3, schunk = tid & 7;      // A staging
    const int bcol = tid & 63, bkg = tid >> 6;        // B staging (col, k-grp)
    const int bsw  = (bcol & 7) << 4;                 // B LDS XOR swizzle

    f32x4 acc[4][4];
    #pragma unroll
    for (int m = 0; m < 4; ++m)
        #pragma unroll
        for (int n = 0; n < 4; ++n) { f32x4 z = {0.f,0.f,0.f,0.f}; acc[m][n] = z; }

    const unsigned short* Ag = A + (size_t)srow * 1024 + schunk * 8;

    auto stageA = [&](unsigned short* la_, int t) {
        char* la = (char*)la_ + tid * 16;
        #pragma unroll
        for (int i = 0; i < 8; ++i)
            gload16(Ag + (size_t)(32 * i) * 1024 + t * 64, la + i * 4096);
    };
    float bv_[16];
    auto loadB = [&](int t) {
        const float* src = Wout + (size_t)(t * 64 + bkg * 16) * 32000 + n0 + bcol;
        #pragma unroll
        for (int j = 0; j < 16; ++j) bv_[j] = src[(size_t)j * 32000];
    };
    auto writeB = [&](unsigned short* lb_) {
        ushort8 o0, o1;
        #pragma unroll
        for (int j = 0; j < 8; ++j) { o0[j] = f2bf(bv_[j]); o1[j] = f2bf(bv_[j + 8]); }
        char* base = (char*)lb_ + bcol * 128;
        *(ushort8*)(base + ((bkg * 32)      ^ bsw)) = o0;
        *(ushort8*)(base + ((bkg * 32 + 16) ^ bsw)) = o1;
    };
    auto compute = [&](const unsigned short* la_, const unsigned short* lb_) {
        #pragma unroll
        for (int kk = 0; kk < 2; ++kk) {
            bf16x8 af[4], bv[4];
            #pragma unroll
            for (int m = 0; m < 4; ++m)
                af[m] = *(const bf16x8*)((const char*)la_ +
                          (wave * 64 + m * 16 + lm) * 128 + (kk * 32 + lk) * 2);
            #pragma unroll
            for (int n = 0; n < 4; ++n) {
                int rr = n * 16 + lm;
                bv[n] = *(const bf16x8*)((const char*)lb_ +
                          rr * 128 + (((kk * 32 + lk) * 2) ^ ((rr & 7) << 4)));
            }
            #pragma unroll
            for (int m = 0; m < 4; ++m)
                #pragma unroll
                for (int n = 0; n < 4; ++n)
                    acc[m][n] = __builtin_amdgcn_mfma_f32_16x16x32_bf16(
                        af[m], bv[n], acc[m][n], 0, 0, 0);
        }
    };

    stageA(lA0, 0); loadB(0); writeB(lB0);
    __syncthreads();
    const int nt = 16;                                 // K=1024 / 64
    for (int t = 0; t < nt; t += 2) {
        if (t + 1 < nt) { stageA(lA1, t + 1); loadB(t + 1); }
        compute(lA0, lB0);
        if (t + 1 < nt) writeB(lB1);
        __syncthreads();
        if (t + 1 < nt) {
            if (t + 2 < nt) { stageA(lA0, t + 2); loadB(t + 2); }
            compute(lA1, lB1);
            if (t + 2 < nt) writeB(lB0);
            __syncthreads();
        }
    }

    const int rbase = wave * 64 + (lane >> 4) * 4;
    const int cbase = n0 + lm;
    #pragma unroll
    for (int m = 0; m < 4; ++m) {
        #pragma unroll
        for (int n = 0; n < 4; ++n) {
            int col = cbase + n * 16;
            float bvv = bias[col];
            #pragma unroll
            for (int j = 0; j < 4; ++j)
                C[(size_t)(rbase + m * 16 + j) * 32000 + col] = acc[m][n][j] + bvv;
        }
    }
}

// ---------------- G5 split-K16 reduce + bias -> bf16 x ----------------------
__global__ __launch_bounds__(256) void reduce5_kernel(
    const float* __restrict__ P, const float* __restrict__ bias,
    unsigned short* __restrict__ xb)
{
    int i = blockIdx.x * 256 + threadIdx.x;        // 131072 float4s
    const float4* p = (const float4*)P;
    float4 bb = ((const float4*)bias)[i & 511];
    float s0 = bb.x, s1 = bb.y, s2 = bb.z, s3 = bb.w;
    #pragma unroll
    for (int s = 0; s < 16; ++s) {
        float4 v = p[i + s * 131072];
        s0 += v.x; s1 += v.y; s2 += v.z; s3 += v.w;
    }
    ((ushort4*)xb)[i] = make_ushort4(f2bf(s0), f2bf(s1), f2bf(s2), f2bf(s3));
}

// ---------------- GRU pointwise + split-K reduce (gate order r,z,n) ---------
__global__ __launch_bounds__(256) void gru_kernel(
    const float* __restrict__ pg, const float* __restrict__ b_ih,
    const float* __restrict__ b_hh, const float* __restrict__ h,
    unsigned short* __restrict__ hnewb)
{
    int idx = blockIdx.x * 256 + threadIdx.x;       // 262144
    int b = idx >> 10, j = idx & 1023;
    float ir = b_ih[j], iz = b_ih[1024 + j], in_ = b_ih[2048 + j];
    float hr = b_hh[j], hz = b_hh[1024 + j], hn  = b_hh[2048 + j];
    #pragma unroll
    for (int s = 0; s < 4; ++s) {
        const float* gi = pg + (size_t)s * 786432 + (size_t)b * 3072;
        ir  += gi[j]; iz += gi[1024 + j]; in_ += gi[2048 + j];
        const float* gh = pg + (size_t)(4 + s) * 786432 + (size_t)b * 3072;
        hr  += gh[j]; hz += gh[1024 + j]; hn  += gh[2048 + j];
    }
    float r = 1.f / (1.f + expf(-(ir + hr)));
    float z = 1.f / (1.f + expf(-(iz + hz)));
    float n = tanhf(in_ + r * hn);
    hnewb[idx] = f2bf((1.f - z) * n + z * h[idx]);
}

// ---------------------------------------------------------------------------
extern "C" void kernel_launch(void* const* d_in, const int* in_sizes, int n_in,
                              void* d_out, int out_size, void* d_ws, size_t ws_size,
                              hipStream_t stream)
{
    const int*   input_ids    = (const int*)  d_in[0];
    const float* hidden       = (const float*)d_in[1];
    const float* enc_out      = (const float*)d_in[2];
    const int*   input_tensor = (const int*)  d_in[3];
    const int*   pairing_ids  = (const int*)  d_in[4];
    const float* emb_dec      = (const float*)d_in[5];
    const float* enc_emb      = (const float*)d_in[6];
    const float* Wq_i  = (const float*)d_in[7];
    const float* Wk_i  = (const float*)d_in[8];
    const float* wa_i  = (const float*)d_in[9];
    const float* Wq_p  = (const float*)d_in[10];
    const float* Wk_p  = (const float*)d_in[11];
    const float* wa_p  = (const float*)d_in[12];
    const float* ba_p  = (const float*)d_in[13];
    const float* W_lin = (const float*)d_in[14];
    const float* b_lin = (const float*)d_in[15];
    const float* W_ih  = (const float*)d_in[16];
    const float* W_hh  = (const float*)d_in[17];
    const float* b_ih  = (const float*)d_in[18];
    const float* b_hh  = (const float*)d_in[19];
    const float* W_out = (const float*)d_in[20];
    const float* b_out = (const float*)d_in[21];

    // ---- workspace layout (time-shared slots, lifetimes serial) ------------
    constexpr size_t OFF_HB    = 0;            // bf16 h, alive all
    constexpr size_t OFF_HNEW  = 524288;       // bf16 h_new, gru..G8
    constexpr size_t OFF_WQI   = 1048576;      // WqiT 2MB (..dual)
    constexpr size_t OFF_WQP   = 3145728;      // WqpT 2MB (..dual)
    constexpr size_t OFF_WKI   = 5242880;      // WkiT 4MB (..gemm24p)
    constexpr size_t OFF_WKP   = 9437184;      // WkpT 4MB (..gemm24p)
    constexpr size_t OFF_ENC   = 13631488;     // encb 21MB (..gemm24p)
    constexpr size_t OFF_SLOT1 = 34603008;     // kpP 2x10.5MB (gemm24p..gather2)
                                               //   -> outp/xb
    constexpr size_t OFF_SLOT2 = 55574528;     // encembb (..gemm24p)
    constexpr size_t OFF_SCI   = 78643200;     // 24KB
    constexpr size_t OFF_SCP   = 78667776;     // 20KB
    constexpr size_t OFF_PGI   = 1048576;      // G67 partials 8x3MB=24MB
                                               //   ([1M,34.6M) free after gemm24p)
    constexpr size_t NEED      = 79167488;
    if (ws_size < NEED) {
        fprintf(stderr, "kernel_launch: ws_size %zu < needed %zu\n", ws_size, NEED);
        return;
    }
    char* ws = (char*)d_ws;
    unsigned short* hb     = (unsigned short*)(ws + OFF_HB);
    unsigned short* hnewb  = (unsigned short*)(ws + OFF_HNEW);
    unsigned short* WqiT   = (unsigned short*)(ws + OFF_WQI);
    unsigned short* WqpT   = (unsigned short*)(ws + OFF_WQP);
    unsigned short* WkiT   = (unsigned short*)(ws + OFF_WKI);
    unsigned short* WkpT   = (unsigned short*)(ws + OFF_WKP);
    unsigned short* encb   = (unsigned short*)(ws + OFF_ENC);
    unsigned short* kpP    = (unsigned short*)(ws + OFF_SLOT1);
    unsigned short* encembb= (unsigned short*)(ws + OFF_SLOT2);
    unsigned short* outp   = (unsigned short*)(ws + OFF_SLOT1);          // after gather2
    unsigned short* xb     = (unsigned short*)(ws + OFF_SLOT1 + 18350080);  // 1MB
    float*          sc_i   = (float*)         (ws + OFF_SCI);
    float*          sc_p   = (float*)         (ws + OFF_SCP);
    float*          pgi    = (float*)         (ws + OFF_PGI);
    // d_out (32.77MB) scratch until gemm8 overwrites it:
    //   keyP [0,21MB); pqQ [21,25.2MB); pqP [25.2,29.4MB); then pG5 [0,32MB)
    unsigned short* keyP   = (unsigned short*)d_out;
    float*          pqQ    = (float*)((char*)d_out + 20971520);
    float*          pqP    = (float*)((char*)d_out + 20971520 + 4194304);
    float*          pG5    = (float*)d_out;

    constexpr size_t KP_STRIDE = 5120 * 1024;   // elements per partial slice

    // 1. prep1: all converts + Wq/Wk transposes (one launch)
    prep1_kernel<<<22032, 256, 0, stream>>>(hidden, enc_out, enc_emb,
                                            Wq_i, Wq_p, Wk_i, Wk_p,
                                            hb, encb, encembb,
                                            WqiT, WqpT, WkiT, WkpT);

    // 2. dual split-K4: q partials -> d_out tail (reduce folded into scores)
    gemm_dual_kernel<<<dim3(8, 2, 8), 256, 0, stream>>>(hb, WqiT, WqpT, pqQ, pqP);

    // 3. gemm24p (counted-vmcnt + XCD remap): kpP -> SLOT1, keyP -> d_out
    gemm24p_kernel<<<1280, 256, 0, stream>>>(encembb, encb, WkpT, WkiT,
                                             kpP, keyP, KP_STRIDE);

    // 4-5. ingredient scores (q-reduce folded); pairing scores (qp-reduce folded)
    attn_scores2q_kernel<<<5120, 256, 0, stream>>>(pqQ, keyP, KP_STRIDE, wa_i, sc_i);
    attn_scores_gather2q_kernel<<<5120, 256, 0, stream>>>(pqP, kpP, KP_STRIDE, wa_p, ba_p,
                                                          sc_i, input_tensor, pairing_ids, sc_p);

    // 6. out_pair = [emb | softmax(s)*s @ enc_emb-gather]  (overwrites kpP)
    out_pair_kernel<<<1536, 256, 0, stream>>>(sc_p, enc_emb, sc_i, input_tensor,
                                              pairing_ids, emb_dec, input_ids, outp);

    // 7-8. G5 fused (W_lin f32 in-GEMM): split-K16 -> partials in d_out -> xb
    gemm5f_kernel<<<dim3(16, 2, 16), 256, 0, stream>>>(outp, W_lin, pG5);
    reduce5_kernel<<<512, 256, 0, stream>>>(pG5, b_lin, xb);

    // 9. G6+G7 fused (W_ih/W_hh f32 in-GEMM), split-K4 each
    gemm67f_kernel<<<dim3(24, 2, 8), 256, 0, stream>>>(xb, hb, W_ih, W_hh, pgi);

    // 10. GRU pointwise (+ split-K reduce + biases) -> h_new bf16
    gru_kernel<<<1024, 256, 0, stream>>>(pgi, b_ih, b_hh, hidden, hnewb);

    // 11. G8 fused: logits = h_new @ W_out + b_out (overwrites d_out scratch)
    gemm8_kernel<<<500, 256, 0, stream>>>(hnewb, W_out, b_out, (float*)d_out);
}